// Round 7
// baseline (587.393 us; speedup 1.0000x reference)
//
#include <hip/hip_runtime.h>
#include <math.h>

#define N2C 16000
#define N1C 4000
#define N0C 1000
#define DEG 32
#define CH 256      // H*O
#define NHEAD 4
#define ODIM 64
#define ALPHA 0.2f
#define LDP 264     // padded LDS row pitch (ushorts): 528 B, 16B-aligned, 2-way banks
#define EPAD 36     // padded edge count (33 real + 3 zero-weight pads)
#define GRIDN 512   // 2 blocks/CU x 256 CUs; __launch_bounds__(256,2) guarantees fit

typedef __attribute__((ext_vector_type(8))) short bf16x8;
typedef __attribute__((ext_vector_type(4))) float f32x4;

__device__ __forceinline__ ushort f2bf(float f) {
    unsigned u = __float_as_uint(f);
    unsigned r = (u + 0x7fffu + ((u >> 16) & 1u)) >> 16;   // RTNE
    return (ushort)r;
}
__device__ __forceinline__ float bf2f(ushort h) {
    return __uint_as_float(((unsigned)h) << 16);
}

// ---- manual grid barrier: one fresh counter per sync point (no reset/reuse) --------
// Device-scope fences handle cross-XCD L2 non-coherence (G16). Bounded spin: a
// co-residency failure produces a wrong answer (visible), never a hang.
__device__ __forceinline__ void grid_barrier(unsigned* bar, int idx) {
    __syncthreads();
    if (threadIdx.x == 0) {
        __threadfence();                                   // release: L2 writeback
        __hip_atomic_fetch_add(bar + idx, 1u, __ATOMIC_RELEASE, __HIP_MEMORY_SCOPE_AGENT);
        int spins = 0;
        while (__hip_atomic_load(bar + idx, __ATOMIC_ACQUIRE, __HIP_MEMORY_SCOPE_AGENT)
               < (unsigned)GRIDN) {
            __builtin_amdgcn_s_sleep(2);
            if (++spins > 500000) break;                   // ~100 ms failsafe
        }
        __threadfence();                                   // acquire: invalidate stale
    }
    __syncthreads();
}

__global__ __launch_bounds__(64) void init_kernel(unsigned* bar) {
    if (threadIdx.x < 8) bar[threadIdx.x] = 0;             // ws is 0xAA-poisoned
}

// ---------------- split-bf16 MFMA GEMM tile + fused score epilogue ------------------
template<int RT, int EPI, int AF32, int SC>
__device__ __forceinline__ void gemm_tile(
    int tileIdx, int M,
    const float* __restrict__ Af,
    const ushort* __restrict__ Ah, const ushort* __restrict__ Al,
    const ushort* __restrict__ Bh, const ushort* __restrict__ Bl,
    const float* __restrict__ bias, const float* __restrict__ avec,
    float* __restrict__ out, float* __restrict__ s_t, float* __restrict__ s_n,
    ushort* sah, ushort* sal)
{
    const int wave = threadIdx.x >> 6;
    const int lane = threadIdx.x & 63;
    const int quad = lane >> 4, l16 = lane & 15;
    const int row0 = tileIdx * (RT * 16);
    const int col0 = wave * 64;

    if (AF32) {
        for (int idx = threadIdx.x; idx < RT * 16 * 64; idx += 256) {
            int row = idx >> 6, c4 = idx & 63;
            int gr = row0 + row; if (gr >= M) gr = M - 1;
            float4 f = ((const float4*)Af)[gr * 64 + c4];
            ushort4 h, l;
            h.x = f2bf(f.x); l.x = f2bf(f.x - bf2f(h.x));
            h.y = f2bf(f.y); l.y = f2bf(f.y - bf2f(h.y));
            h.z = f2bf(f.z); l.z = f2bf(f.z - bf2f(h.z));
            h.w = f2bf(f.w); l.w = f2bf(f.w - bf2f(h.w));
            *(ushort4*)(&sah[row * LDP + c4 * 4]) = h;
            *(ushort4*)(&sal[row * LDP + c4 * 4]) = l;
        }
        __syncthreads();
    }

    f32x4 acc[RT][4];
#pragma unroll
    for (int r = 0; r < RT; ++r)
#pragma unroll
        for (int c = 0; c < 4; ++c) acc[r][c] = (f32x4){0.f, 0.f, 0.f, 0.f};

    int arow[RT];
#pragma unroll
    for (int r = 0; r < RT; ++r) {
        int rr = row0 + r * 16 + l16;
        arow[r] = (rr < M) ? rr : (M - 1);
    }
    const int kbase = quad * 8;

    for (int k0 = 0; k0 < 256; k0 += 32) {
        bf16x8 a_h[RT], a_l[RT], b_h[4], b_l[4];
#pragma unroll
        for (int r = 0; r < RT; ++r) {
            if (AF32) {
                int loff = (r * 16 + l16) * LDP + k0 + kbase;
                a_h[r] = *(const bf16x8*)(&sah[loff]);
                a_l[r] = *(const bf16x8*)(&sal[loff]);
            } else {
                int off = arow[r] * 256 + k0 + kbase;
                a_h[r] = *(const bf16x8*)(Ah + off);
                a_l[r] = *(const bf16x8*)(Al + off);
            }
        }
#pragma unroll
        for (int c = 0; c < 4; ++c) {
            int off = (col0 + c * 16 + l16) * 256 + k0 + kbase;
            b_h[c] = *(const bf16x8*)(Bh + off);
            b_l[c] = *(const bf16x8*)(Bl + off);
        }
#pragma unroll
        for (int r = 0; r < RT; ++r)
#pragma unroll
            for (int c = 0; c < 4; ++c) {
                acc[r][c] = __builtin_amdgcn_mfma_f32_16x16x32_bf16(a_h[r], b_h[c], acc[r][c], 0, 0, 0);
                acc[r][c] = __builtin_amdgcn_mfma_f32_16x16x32_bf16(a_h[r], b_l[c], acc[r][c], 0, 0, 0);
                acc[r][c] = __builtin_amdgcn_mfma_f32_16x16x32_bf16(a_l[r], b_h[c], acc[r][c], 0, 0, 0);
            }
    }

    // C/D layout: col = lane&15, row = quad*4 + reg  [measured m89/m91]
#pragma unroll
    for (int r = 0; r < RT; ++r)
#pragma unroll
        for (int c = 0; c < 4; ++c) {
            int col = col0 + c * 16 + l16;
#pragma unroll
            for (int reg = 0; reg < 4; ++reg) {
                int row = row0 + r * 16 + quad * 4 + reg;
                if (row < M) {
                    float v = acc[r][c][reg];
                    if (EPI == 1) v = tanhf(v + bias[col]);
                    out[row * 256 + col] = v;
                }
            }
        }

    if (SC) {
        float at[4], an[4];
#pragma unroll
        for (int c = 0; c < 4; ++c) {
            at[c] = avec[wave * 128 + c * 16 + l16];
            an[c] = avec[wave * 128 + 64 + c * 16 + l16];
        }
#pragma unroll
        for (int r = 0; r < RT; ++r) {
            float pt[4] = {0.f, 0.f, 0.f, 0.f}, pn[4] = {0.f, 0.f, 0.f, 0.f};
#pragma unroll
            for (int c = 0; c < 4; ++c)
#pragma unroll
                for (int reg = 0; reg < 4; ++reg) {
                    pt[reg] += acc[r][c][reg] * at[c];
                    pn[reg] += acc[r][c][reg] * an[c];
                }
#pragma unroll
            for (int reg = 0; reg < 4; ++reg)
#pragma unroll
                for (int m = 1; m < 16; m <<= 1) {
                    pt[reg] += __shfl_xor(pt[reg], m);
                    pn[reg] += __shfl_xor(pn[reg], m);
                }
            if (l16 == 0) {
#pragma unroll
                for (int reg = 0; reg < 4; ++reg) {
                    int row = row0 + r * 16 + quad * 4 + reg;
                    if (row < M) {
                        s_t[wave * M + row] = pt[reg];
                        s_n[wave * M + row] = pn[reg];
                    }
                }
            }
        }
    }
}

// ---------------- per-target attention: dedupe+softmax (wave-parallel), gather ------
__device__ __forceinline__ void att_tile(
    int tgt,
    const float* __restrict__ hprev, const int* __restrict__ nbr_arr,
    const float* __restrict__ s_t, const float* __restrict__ s_n,
    ushort* __restrict__ outhi, ushort* __restrict__ outlo, int T, int Nsrc,
    int* nbr, float (*att_s)[EPAD], float4 (*red)[64])
{
    const int t = threadIdx.x;
    const int lane = t & 63;
    if (t < DEG) nbr[t] = nbr_arr[tgt * DEG + t];
    else if (t == DEG) nbr[DEG] = nbr_arr[T * DEG + tgt];  // self-loop edge
    else if (t < EPAD) nbr[t] = 0;                          // pad: valid row, weight 0
    __syncthreads();

    {   // wave = head; lane = edge index (33 edges), lanes 33..63 inert
        const int hd = t >> 6;
        int me = (lane <= DEG) ? nbr[lane] : 0;
        int k = (lane <= DEG) ? 1 : 0;
#pragma unroll
        for (int j = 0; j < DEG; ++j) {          // dedupe scan via shuffle
            int v = __shfl(me, j);
            if (j < lane && v == me && lane <= DEG) k = 0;
        }
        float e = s_t[hd * Nsrc + tgt] + s_n[hd * Nsrc + me];
        e = (e >= 0.f) ? e : ALPHA * e;          // LeakyReLU(0.2)
        float em = k ? e : -1e30f;
        float m = em;
#pragma unroll
        for (int off = 1; off < 64; off <<= 1) m = fmaxf(m, __shfl_xor(m, off));
        float w = k ? __expf(e - m) : 0.f;
        float Z = w;
#pragma unroll
        for (int off = 1; off < 64; off <<= 1) Z += __shfl_xor(Z, off);
        if (lane < EPAD) att_s[hd][lane] = (lane <= DEG) ? (w / Z) : 0.f;
    }
    __syncthreads();

    const int cq = t & 63;
    const int rg = t >> 6;
    const int hd = cq >> 4;
    const float4* hp4 = (const float4*)hprev;
    float w[9];
    int rrow[9];
#pragma unroll
    for (int ii = 0; ii < 9; ++ii) {
        w[ii] = att_s[hd][rg * 9 + ii];
        rrow[ii] = nbr[rg * 9 + ii];
    }
    float4 acc = make_float4(0.f, 0.f, 0.f, 0.f);
#pragma unroll
    for (int ii = 0; ii < 9; ++ii) {
        float4 v = hp4[(size_t)rrow[ii] * 64 + cq];
        acc.x += w[ii] * v.x; acc.y += w[ii] * v.y;
        acc.z += w[ii] * v.z; acc.w += w[ii] * v.w;
    }
    red[rg][cq] = acc;
    __syncthreads();
    if (t < 64) {
        float4 s0 = red[0][t], s1 = red[1][t], s2 = red[2][t], s3 = red[3][t];
        float4 s;
        s.x = s0.x + s1.x + s2.x + s3.x;
        s.y = s0.y + s1.y + s2.y + s3.y;
        s.z = s0.z + s1.z + s2.z + s3.z;
        s.w = s0.w + s1.w + s2.w + s3.w;
        s.x = (s.x > 0.f) ? s.x : expm1f(s.x);   // ELU
        s.y = (s.y > 0.f) ? s.y : expm1f(s.y);
        s.z = (s.z > 0.f) ? s.z : expm1f(s.z);
        s.w = (s.w > 0.f) ? s.w : expm1f(s.w);
        ushort4 h, l;
        h.x = f2bf(s.x); l.x = f2bf(s.x - bf2f(h.x));
        h.y = f2bf(s.y); l.y = f2bf(s.y - bf2f(h.y));
        h.z = f2bf(s.z); l.z = f2bf(s.z - bf2f(h.z));
        h.w = f2bf(s.w); l.w = f2bf(s.w - bf2f(h.w));
        ((ushort4*)outhi)[tgt * 64 + t] = h;
        ((ushort4*)outlo)[tgt * 64 + t] = l;
    }
    __syncthreads();
}

// ---------------- single mega-kernel (plain launch + manual grid barriers) ----------
__global__ __launch_bounds__(256, 2) void mega_kernel(
    const float* __restrict__ x,
    const float* __restrict__ W0, const float* __restrict__ a0,
    const float* __restrict__ W1, const float* __restrict__ a1,
    const float* __restrict__ linW, const float* __restrict__ linb,
    const int* __restrict__ adj1_nbr, const int* __restrict__ adj0_nbr,
    char* __restrict__ ws, float* __restrict__ dout)
{
    __shared__ ushort sah[2 * 16 * LDP];
    __shared__ ushort sal[2 * 16 * LDP];
    __shared__ int nbr[EPAD];
    __shared__ float att_s[NHEAD][EPAD];
    __shared__ float4 red[4][64];

    const int bid = blockIdx.x;

    // workspace layout (bytes)
    ushort* Wth = (ushort*)ws;                         // 0       .. 393216
    ushort* Wtl = Wth + 3 * 65536;                     // 393216  .. 786432
    float*  st  = (float*)(ws + 786432);               // 786432  .. 1042432 (4*16000 f32)
    float*  sn  = (float*)(ws + 1048576);              // 1048576 .. 1304576
    unsigned* bar = (unsigned*)(ws + 1304576);         // 8 counters (init_kernel zeroes)
    float*  h0  = (float*)(ws + 1310720);              // 16000*256 f32 (reused as h1)
    ushort* xhi = (ushort*)(ws + 1310720 + 16384000);  // att outputs (bf16 hi/lo)
    ushort* xlo = xhi + 4096000;

    // stage 0: repack weights -> bf16 hi/lo, transposed [n][k]
    for (int g = bid * 256 + threadIdx.x; g < 3 * 65536; g += GRIDN * 256) {
        int mat = g >> 16;
        int idx = g & 65535;
        int c = idx >> 8, k = idx & 255;
        float v;
        if (mat == 0)      v = W0[(c >> 6) * (256 * 64) + k * 64 + (c & 63)];
        else if (mat == 1) v = W1[(c >> 6) * (256 * 64) + k * 64 + (c & 63)];
        else               v = linW[c * 256 + k];
        ushort h = f2bf(v);
        Wth[g] = h;
        Wtl[g] = f2bf(v - bf2f(h));
    }
    grid_barrier(bar, 0);

    // stage 1: h0 = x @ Wc0 (+ fused scores), 500 tiles of 32 rows
    for (int tile = bid; tile < N2C / 32; tile += GRIDN)
        gemm_tile<2, 0, 1, 1>(tile, N2C, x, nullptr, nullptr, Wth, Wtl,
                              nullptr, a0, h0, st, sn, sah, sal);
    grid_barrier(bar, 1);

    // stage 2: attention layer 1 -> x1 (bf16 hi/lo)
    for (int tgt = bid; tgt < N1C; tgt += GRIDN)
        att_tile(tgt, h0, adj1_nbr, st, sn, xhi, xlo, N1C, N2C, nbr, att_s, red);
    grid_barrier(bar, 2);

    // stage 3: h1 = x1 @ Wc1 (+ fused scores), 250 tiles of 16 rows
    for (int tile = bid; tile < N1C / 16; tile += GRIDN)
        gemm_tile<1, 0, 0, 1>(tile, N1C, nullptr, xhi, xlo, Wth + 65536, Wtl + 65536,
                              nullptr, a1, h0, st, sn, sah, sal);
    grid_barrier(bar, 3);

    // stage 4: attention layer 0 -> x2 (bf16 hi/lo, overwrites x1 rows 0..999)
    for (int tgt = bid; tgt < N0C; tgt += GRIDN)
        att_tile(tgt, h0, adj0_nbr, st, sn, xhi, xlo, N0C, N1C, nbr, att_s, red);
    grid_barrier(bar, 4);

    // stage 5: out = tanh(x2 @ linW^T + b), 63 tiles of 16 rows
    for (int tile = bid; tile < (N0C + 15) / 16; tile += GRIDN)
        gemm_tile<1, 1, 0, 0>(tile, N0C, nullptr, xhi, xlo, Wth + 131072, Wtl + 131072,
                              linb, nullptr, dout, nullptr, nullptr, sah, sal);
}

extern "C" void kernel_launch(void* const* d_in, const int* in_sizes, int n_in,
                              void* d_out, int out_size, void* d_ws, size_t ws_size,
                              hipStream_t stream)
{
    const float* x    = (const float*)d_in[0];
    const float* W0   = (const float*)d_in[1];
    const float* a0   = (const float*)d_in[2];
    const float* W1   = (const float*)d_in[3];
    const float* a1   = (const float*)d_in[4];
    const float* linW = (const float*)d_in[5];
    const float* linb = (const float*)d_in[6];
    const int* adj1_nbr = (const int*)d_in[8];
    const int* adj0_nbr = (const int*)d_in[10];
    char* ws = (char*)d_ws;

    init_kernel<<<1, 64, 0, stream>>>((unsigned*)(ws + 1304576));
    mega_kernel<<<GRIDN, 256, 0, stream>>>(
        x, W0, a0, W1, a1, linW, linb, adj1_nbr, adj0_nbr, ws, (float*)d_out);
}

// Round 8
// 390.359 us; speedup vs baseline: 1.5048x; 1.5048x over previous
//
#include <hip/hip_runtime.h>
#include <math.h>

#define N2C 16000
#define N1C 4000
#define N0C 1000
#define DEG 32
#define CH 256      // H*O
#define NHEAD 4
#define ODIM 64
#define ALPHA 0.2f
#define LDP 264     // padded LDS row pitch (ushorts): 528 B, 16B-aligned, 2-way banks
#define EPAD 36     // padded edge count (33 real + 3 zero-weight pads)
#define GRIDN 512   // 2 blocks/CU x 256 CUs; __launch_bounds__(256,2) guarantees fit

typedef __attribute__((ext_vector_type(8))) short bf16x8;
typedef __attribute__((ext_vector_type(4))) float f32x4;

__device__ __forceinline__ ushort f2bf(float f) {
    unsigned u = __float_as_uint(f);
    unsigned r = (u + 0x7fffu + ((u >> 16) & 1u)) >> 16;   // RTNE
    return (ushort)r;
}
__device__ __forceinline__ float bf2f(ushort h) {
    return __uint_as_float(((unsigned)h) << 16);
}

// ---- manual grid barrier ----------------------------------------------------------
// R7 lesson: ACQUIRE poll emits buffer_inv per iteration -> L2-invalidate storm
// (~100 us/barrier). Fix: RELAXED poll, ONE acquire fence after the loop exits.
__device__ __forceinline__ void grid_barrier(unsigned* bar, int idx) {
    __syncthreads();
    if (threadIdx.x == 0) {
        __threadfence();                                   // release: L2 writeback
        __hip_atomic_fetch_add(bar + idx, 1u, __ATOMIC_RELAXED, __HIP_MEMORY_SCOPE_AGENT);
        int spins = 0;
        while (__hip_atomic_load(bar + idx, __ATOMIC_RELAXED, __HIP_MEMORY_SCOPE_AGENT)
               < (unsigned)GRIDN) {
            __builtin_amdgcn_s_sleep(1);
            if (++spins > 2000000) break;                  // failsafe: fail visibly, no hang
        }
        __threadfence();                                   // acquire: one-time invalidate
    }
    __syncthreads();
}

// ---------------- launch 1: repack weights + zero barrier counters ------------------
__global__ __launch_bounds__(256) void repack_kernel(
    const float* __restrict__ W0, const float* __restrict__ W1,
    const float* __restrict__ linW,
    ushort* __restrict__ Wth, ushort* __restrict__ Wtl, unsigned* __restrict__ bar)
{
    if (blockIdx.x == 0 && threadIdx.x < 8) bar[threadIdx.x] = 0;  // ws is 0xAA-poisoned
    int g = blockIdx.x * 256 + threadIdx.x;   // 0 .. 3*65536-1
    int mat = g >> 16;
    int idx = g & 65535;
    int c = idx >> 8, k = idx & 255;
    float v;
    if (mat == 0)      v = W0[(c >> 6) * (256 * 64) + k * 64 + (c & 63)];
    else if (mat == 1) v = W1[(c >> 6) * (256 * 64) + k * 64 + (c & 63)];
    else               v = linW[c * 256 + k];
    ushort h = f2bf(v);
    Wth[g] = h;
    Wtl[g] = f2bf(v - bf2f(h));
}

// ---------------- split-bf16 MFMA GEMM tile + fused score epilogue ------------------
template<int RT, int EPI, int AF32, int SC>
__device__ __forceinline__ void gemm_tile(
    int tileIdx, int M,
    const float* __restrict__ Af,
    const ushort* __restrict__ Ah, const ushort* __restrict__ Al,
    const ushort* __restrict__ Bh, const ushort* __restrict__ Bl,
    const float* __restrict__ bias, const float* __restrict__ avec,
    float* __restrict__ out, float* __restrict__ s_t, float* __restrict__ s_n,
    ushort* sah, ushort* sal)
{
    const int wave = threadIdx.x >> 6;
    const int lane = threadIdx.x & 63;
    const int quad = lane >> 4, l16 = lane & 15;
    const int row0 = tileIdx * (RT * 16);
    const int col0 = wave * 64;

    if (AF32) {
        for (int idx = threadIdx.x; idx < RT * 16 * 64; idx += 256) {
            int row = idx >> 6, c4 = idx & 63;
            int gr = row0 + row; if (gr >= M) gr = M - 1;
            float4 f = ((const float4*)Af)[gr * 64 + c4];
            ushort4 h, l;
            h.x = f2bf(f.x); l.x = f2bf(f.x - bf2f(h.x));
            h.y = f2bf(f.y); l.y = f2bf(f.y - bf2f(h.y));
            h.z = f2bf(f.z); l.z = f2bf(f.z - bf2f(h.z));
            h.w = f2bf(f.w); l.w = f2bf(f.w - bf2f(h.w));
            *(ushort4*)(&sah[row * LDP + c4 * 4]) = h;
            *(ushort4*)(&sal[row * LDP + c4 * 4]) = l;
        }
        __syncthreads();
    }

    f32x4 acc[RT][4];
#pragma unroll
    for (int r = 0; r < RT; ++r)
#pragma unroll
        for (int c = 0; c < 4; ++c) acc[r][c] = (f32x4){0.f, 0.f, 0.f, 0.f};

    int arow[RT];
#pragma unroll
    for (int r = 0; r < RT; ++r) {
        int rr = row0 + r * 16 + l16;
        arow[r] = (rr < M) ? rr : (M - 1);
    }
    const int kbase = quad * 8;

    for (int k0 = 0; k0 < 256; k0 += 32) {
        bf16x8 a_h[RT], a_l[RT], b_h[4], b_l[4];
#pragma unroll
        for (int r = 0; r < RT; ++r) {
            if (AF32) {
                int loff = (r * 16 + l16) * LDP + k0 + kbase;
                a_h[r] = *(const bf16x8*)(&sah[loff]);
                a_l[r] = *(const bf16x8*)(&sal[loff]);
            } else {
                int off = arow[r] * 256 + k0 + kbase;
                a_h[r] = *(const bf16x8*)(Ah + off);
                a_l[r] = *(const bf16x8*)(Al + off);
            }
        }
#pragma unroll
        for (int c = 0; c < 4; ++c) {
            int off = (col0 + c * 16 + l16) * 256 + k0 + kbase;
            b_h[c] = *(const bf16x8*)(Bh + off);
            b_l[c] = *(const bf16x8*)(Bl + off);
        }
#pragma unroll
        for (int r = 0; r < RT; ++r)
#pragma unroll
            for (int c = 0; c < 4; ++c) {
                acc[r][c] = __builtin_amdgcn_mfma_f32_16x16x32_bf16(a_h[r], b_h[c], acc[r][c], 0, 0, 0);
                acc[r][c] = __builtin_amdgcn_mfma_f32_16x16x32_bf16(a_h[r], b_l[c], acc[r][c], 0, 0, 0);
                acc[r][c] = __builtin_amdgcn_mfma_f32_16x16x32_bf16(a_l[r], b_h[c], acc[r][c], 0, 0, 0);
            }
    }

    // C/D layout: col = lane&15, row = quad*4 + reg  [measured m89/m91]
#pragma unroll
    for (int r = 0; r < RT; ++r)
#pragma unroll
        for (int c = 0; c < 4; ++c) {
            int col = col0 + c * 16 + l16;
#pragma unroll
            for (int reg = 0; reg < 4; ++reg) {
                int row = row0 + r * 16 + quad * 4 + reg;
                if (row < M) {
                    float v = acc[r][c][reg];
                    if (EPI == 1) v = tanhf(v + bias[col]);
                    out[row * 256 + col] = v;
                }
            }
        }

    if (SC) {
        float at[4], an[4];
#pragma unroll
        for (int c = 0; c < 4; ++c) {
            at[c] = avec[wave * 128 + c * 16 + l16];
            an[c] = avec[wave * 128 + 64 + c * 16 + l16];
        }
#pragma unroll
        for (int r = 0; r < RT; ++r) {
            float pt[4] = {0.f, 0.f, 0.f, 0.f}, pn[4] = {0.f, 0.f, 0.f, 0.f};
#pragma unroll
            for (int c = 0; c < 4; ++c)
#pragma unroll
                for (int reg = 0; reg < 4; ++reg) {
                    pt[reg] += acc[r][c][reg] * at[c];
                    pn[reg] += acc[r][c][reg] * an[c];
                }
#pragma unroll
            for (int reg = 0; reg < 4; ++reg)
#pragma unroll
                for (int m = 1; m < 16; m <<= 1) {
                    pt[reg] += __shfl_xor(pt[reg], m);
                    pn[reg] += __shfl_xor(pn[reg], m);
                }
            if (l16 == 0) {
#pragma unroll
                for (int reg = 0; reg < 4; ++reg) {
                    int row = row0 + r * 16 + quad * 4 + reg;
                    if (row < M) {
                        s_t[wave * M + row] = pt[reg];
                        s_n[wave * M + row] = pn[reg];
                    }
                }
            }
        }
    }
}

// ---------------- per-target attention: dedupe+softmax (wave-parallel), gather ------
__device__ __forceinline__ void att_tile(
    int tgt,
    const float* __restrict__ hprev, const int* __restrict__ nbr_arr,
    const float* __restrict__ s_t, const float* __restrict__ s_n,
    ushort* __restrict__ outhi, ushort* __restrict__ outlo, int T, int Nsrc,
    int* nbr, float (*att_s)[EPAD], float4 (*red)[64])
{
    const int t = threadIdx.x;
    const int lane = t & 63;
    if (t < DEG) nbr[t] = nbr_arr[tgt * DEG + t];
    else if (t == DEG) nbr[DEG] = nbr_arr[T * DEG + tgt];  // self-loop edge
    else if (t < EPAD) nbr[t] = 0;                          // pad: valid row, weight 0
    __syncthreads();

    {   // wave = head; lane = edge index (33 edges), lanes 33..63 inert
        const int hd = t >> 6;
        int me = (lane <= DEG) ? nbr[lane] : 0;
        int k = (lane <= DEG) ? 1 : 0;
#pragma unroll
        for (int j = 0; j < DEG; ++j) {          // dedupe scan via shuffle
            int v = __shfl(me, j);
            if (j < lane && v == me && lane <= DEG) k = 0;
        }
        float e = s_t[hd * Nsrc + tgt] + s_n[hd * Nsrc + me];
        e = (e >= 0.f) ? e : ALPHA * e;          // LeakyReLU(0.2)
        float em = k ? e : -1e30f;
        float m = em;
#pragma unroll
        for (int off = 1; off < 64; off <<= 1) m = fmaxf(m, __shfl_xor(m, off));
        float w = k ? __expf(e - m) : 0.f;
        float Z = w;
#pragma unroll
        for (int off = 1; off < 64; off <<= 1) Z += __shfl_xor(Z, off);
        if (lane < EPAD) att_s[hd][lane] = (lane <= DEG) ? (w / Z) : 0.f;
    }
    __syncthreads();

    const int cq = t & 63;
    const int rg = t >> 6;
    const int hd = cq >> 4;
    const float4* hp4 = (const float4*)hprev;
    float w[9];
    int rrow[9];
#pragma unroll
    for (int ii = 0; ii < 9; ++ii) {
        w[ii] = att_s[hd][rg * 9 + ii];
        rrow[ii] = nbr[rg * 9 + ii];
    }
    float4 acc = make_float4(0.f, 0.f, 0.f, 0.f);
#pragma unroll
    for (int ii = 0; ii < 9; ++ii) {
        float4 v = hp4[(size_t)rrow[ii] * 64 + cq];
        acc.x += w[ii] * v.x; acc.y += w[ii] * v.y;
        acc.z += w[ii] * v.z; acc.w += w[ii] * v.w;
    }
    red[rg][cq] = acc;
    __syncthreads();
    if (t < 64) {
        float4 s0 = red[0][t], s1 = red[1][t], s2 = red[2][t], s3 = red[3][t];
        float4 s;
        s.x = s0.x + s1.x + s2.x + s3.x;
        s.y = s0.y + s1.y + s2.y + s3.y;
        s.z = s0.z + s1.z + s2.z + s3.z;
        s.w = s0.w + s1.w + s2.w + s3.w;
        s.x = (s.x > 0.f) ? s.x : expm1f(s.x);   // ELU
        s.y = (s.y > 0.f) ? s.y : expm1f(s.y);
        s.z = (s.z > 0.f) ? s.z : expm1f(s.z);
        s.w = (s.w > 0.f) ? s.w : expm1f(s.w);
        ushort4 h, l;
        h.x = f2bf(s.x); l.x = f2bf(s.x - bf2f(h.x));
        h.y = f2bf(s.y); l.y = f2bf(s.y - bf2f(h.y));
        h.z = f2bf(s.z); l.z = f2bf(s.z - bf2f(h.z));
        h.w = f2bf(s.w); l.w = f2bf(s.w - bf2f(h.w));
        ((ushort4*)outhi)[tgt * 64 + t] = h;
        ((ushort4*)outlo)[tgt * 64 + t] = l;
    }
    __syncthreads();
}

// ---------------- launch 2: mega-kernel (plain launch + manual grid barriers) -------
__global__ __launch_bounds__(256, 2) void mega_kernel(
    const float* __restrict__ x,
    const float* __restrict__ a0, const float* __restrict__ a1,
    const float* __restrict__ linb,
    const int* __restrict__ adj1_nbr, const int* __restrict__ adj0_nbr,
    char* __restrict__ ws, float* __restrict__ dout)
{
    __shared__ ushort sah[2 * 16 * LDP];
    __shared__ ushort sal[2 * 16 * LDP];
    __shared__ int nbr[EPAD];
    __shared__ float att_s[NHEAD][EPAD];
    __shared__ float4 red[4][64];

    const int bid = blockIdx.x;

    // workspace layout (bytes)
    ushort* Wth = (ushort*)ws;                         // 0       .. 393216
    ushort* Wtl = Wth + 3 * 65536;                     // 393216  .. 786432
    float*  st  = (float*)(ws + 786432);               // 4*16000 f32
    float*  sn  = (float*)(ws + 1048576);
    unsigned* bar = (unsigned*)(ws + 1304576);         // 8 counters (repack zeroes)
    float*  h0  = (float*)(ws + 1310720);              // 16000*256 f32 (reused as h1)
    ushort* xhi = (ushort*)(ws + 1310720 + 16384000);  // att outputs (bf16 hi/lo)
    ushort* xlo = xhi + 4096000;

    // stage 1: h0 = x @ Wc0 (+ fused scores), 500 tiles of 32 rows
    for (int tile = bid; tile < N2C / 32; tile += GRIDN)
        gemm_tile<2, 0, 1, 1>(tile, N2C, x, nullptr, nullptr, Wth, Wtl,
                              nullptr, a0, h0, st, sn, sah, sal);
    grid_barrier(bar, 1);

    // stage 2: attention layer 1 -> x1 (bf16 hi/lo)
    for (int tgt = bid; tgt < N1C; tgt += GRIDN)
        att_tile(tgt, h0, adj1_nbr, st, sn, xhi, xlo, N1C, N2C, nbr, att_s, red);
    grid_barrier(bar, 2);

    // stage 3: h1 = x1 @ Wc1 (+ fused scores), 250 tiles of 16 rows
    for (int tile = bid; tile < N1C / 16; tile += GRIDN)
        gemm_tile<1, 0, 0, 1>(tile, N1C, nullptr, xhi, xlo, Wth + 65536, Wtl + 65536,
                              nullptr, a1, h0, st, sn, sah, sal);
    grid_barrier(bar, 3);

    // stage 4: attention layer 0 -> x2 (bf16 hi/lo, overwrites x1 rows 0..999)
    for (int tgt = bid; tgt < N0C; tgt += GRIDN)
        att_tile(tgt, h0, adj0_nbr, st, sn, xhi, xlo, N0C, N1C, nbr, att_s, red);
    grid_barrier(bar, 4);

    // stage 5: out = tanh(x2 @ linW^T + b), 63 tiles of 16 rows
    for (int tile = bid; tile < (N0C + 15) / 16; tile += GRIDN)
        gemm_tile<1, 1, 0, 0>(tile, N0C, nullptr, xhi, xlo, Wth + 131072, Wtl + 131072,
                              linb, nullptr, dout, nullptr, nullptr, sah, sal);
}

extern "C" void kernel_launch(void* const* d_in, const int* in_sizes, int n_in,
                              void* d_out, int out_size, void* d_ws, size_t ws_size,
                              hipStream_t stream)
{
    const float* x    = (const float*)d_in[0];
    const float* W0   = (const float*)d_in[1];
    const float* a0   = (const float*)d_in[2];
    const float* W1   = (const float*)d_in[3];
    const float* a1   = (const float*)d_in[4];
    const float* linW = (const float*)d_in[5];
    const float* linb = (const float*)d_in[6];
    const int* adj1_nbr = (const int*)d_in[8];
    const int* adj0_nbr = (const int*)d_in[10];
    char* ws = (char*)d_ws;

    ushort* Wth = (ushort*)ws;
    ushort* Wtl = Wth + 3 * 65536;
    unsigned* bar = (unsigned*)(ws + 1304576);

    repack_kernel<<<768, 256, 0, stream>>>(W0, W1, linW, Wth, Wtl, bar);
    mega_kernel<<<GRIDN, 256, 0, stream>>>(
        x, a0, a1, linb, adj1_nbr, adj0_nbr, ws, (float*)d_out);
}

// Round 9
// 186.522 us; speedup vs baseline: 3.1492x; 2.0928x over previous
//
#include <hip/hip_runtime.h>
#include <math.h>

#define N2C 16000
#define N1C 4000
#define N0C 1000
#define DEG 32
#define NHEAD 4
#define ALPHA 0.2f
#define LDP 264     // padded LDS row pitch (ushorts): 528 B, 16B-aligned, 2-way banks

typedef __attribute__((ext_vector_type(8))) short bf16x8;
typedef __attribute__((ext_vector_type(4))) float f32x4;

__device__ __forceinline__ ushort f2bf(float f) {
    unsigned u = __float_as_uint(f);
    unsigned r = (u + 0x7fffu + ((u >> 16) & 1u)) >> 16;   // RTNE
    return (ushort)r;
}
__device__ __forceinline__ float bf2f(ushort h) {
    return __uint_as_float(((unsigned)h) << 16);
}

// ---------------- launch 1: repack weights -> bf16 hi/lo, transposed [n][k] ---------
__global__ __launch_bounds__(256) void repack_kernel(
    const float* __restrict__ W0, const float* __restrict__ W1,
    const float* __restrict__ linW,
    ushort* __restrict__ Wth, ushort* __restrict__ Wtl)
{
    int g = blockIdx.x * 256 + threadIdx.x;   // 0 .. 3*65536-1
    int mat = g >> 16;
    int idx = g & 65535;
    int c = idx >> 8, k = idx & 255;
    float v;
    if (mat == 0)      v = W0[(c >> 6) * (256 * 64) + k * 64 + (c & 63)];
    else if (mat == 1) v = W1[(c >> 6) * (256 * 64) + k * 64 + (c & 63)];
    else               v = linW[c * 256 + k];
    ushort h = f2bf(v);
    Wth[g] = h;
    Wtl[g] = f2bf(v - bf2f(h));
}

// ---------------- split-bf16 MFMA GEMM tile + fused score epilogue ------------------
// AMODE=1: A fp32 global, staged+converted to LDS hi/lo. AMODE=2: LDS pre-staged.
template<int RT, int EPI, int AMODE, int SC>
__device__ __forceinline__ void gemm_tile(
    int row0, int M,
    const float* __restrict__ Af,
    const ushort* __restrict__ Bh, const ushort* __restrict__ Bl,
    const float* __restrict__ bias, const float* __restrict__ avec,
    float* __restrict__ out, float* __restrict__ s_t, float* __restrict__ s_n,
    ushort* sah, ushort* sal)
{
    const int wave = threadIdx.x >> 6;
    const int lane = threadIdx.x & 63;
    const int quad = lane >> 4, l16 = lane & 15;
    const int col0 = wave * 64;

    if (AMODE == 1) {
        for (int idx = threadIdx.x; idx < RT * 16 * 64; idx += 256) {
            int row = idx >> 6, c4 = idx & 63;
            int gr = row0 + row; if (gr >= M) gr = M - 1;
            float4 f = ((const float4*)Af)[gr * 64 + c4];
            ushort4 h, l;
            h.x = f2bf(f.x); l.x = f2bf(f.x - bf2f(h.x));
            h.y = f2bf(f.y); l.y = f2bf(f.y - bf2f(h.y));
            h.z = f2bf(f.z); l.z = f2bf(f.z - bf2f(h.z));
            h.w = f2bf(f.w); l.w = f2bf(f.w - bf2f(h.w));
            *(ushort4*)(&sah[row * LDP + c4 * 4]) = h;
            *(ushort4*)(&sal[row * LDP + c4 * 4]) = l;
        }
        __syncthreads();
    }

    f32x4 acc[RT][4];
#pragma unroll
    for (int r = 0; r < RT; ++r)
#pragma unroll
        for (int c = 0; c < 4; ++c) acc[r][c] = (f32x4){0.f, 0.f, 0.f, 0.f};

    const int kbase = quad * 8;
    for (int k0 = 0; k0 < 256; k0 += 32) {
        bf16x8 a_h[RT], a_l[RT], b_h[4], b_l[4];
#pragma unroll
        for (int r = 0; r < RT; ++r) {
            int loff = (r * 16 + l16) * LDP + k0 + kbase;
            a_h[r] = *(const bf16x8*)(&sah[loff]);   // ds_read_b128, 2-way banks
            a_l[r] = *(const bf16x8*)(&sal[loff]);
        }
#pragma unroll
        for (int c = 0; c < 4; ++c) {
            int off = (col0 + c * 16 + l16) * 256 + k0 + kbase;
            b_h[c] = *(const bf16x8*)(Bh + off);
            b_l[c] = *(const bf16x8*)(Bl + off);
        }
#pragma unroll
        for (int r = 0; r < RT; ++r)
#pragma unroll
            for (int c = 0; c < 4; ++c) {
                acc[r][c] = __builtin_amdgcn_mfma_f32_16x16x32_bf16(a_h[r], b_h[c], acc[r][c], 0, 0, 0);
                acc[r][c] = __builtin_amdgcn_mfma_f32_16x16x32_bf16(a_h[r], b_l[c], acc[r][c], 0, 0, 0);
                acc[r][c] = __builtin_amdgcn_mfma_f32_16x16x32_bf16(a_l[r], b_h[c], acc[r][c], 0, 0, 0);
            }
    }

    // C/D layout: col = lane&15, row = quad*4 + reg  [measured m89/m91]
#pragma unroll
    for (int r = 0; r < RT; ++r)
#pragma unroll
        for (int c = 0; c < 4; ++c) {
            int col = col0 + c * 16 + l16;
#pragma unroll
            for (int reg = 0; reg < 4; ++reg) {
                int row = row0 + r * 16 + quad * 4 + reg;
                if (row < M) {
                    float v = acc[r][c][reg];
                    if (EPI == 1) v = tanhf(v + bias[col]);
                    out[row * 256 + col] = v;
                }
            }
        }

    if (SC) {   // head == wave; per-lane channels c*16+l16
        float at[4], an[4];
#pragma unroll
        for (int c = 0; c < 4; ++c) {
            at[c] = avec[wave * 128 + c * 16 + l16];
            an[c] = avec[wave * 128 + 64 + c * 16 + l16];
        }
#pragma unroll
        for (int r = 0; r < RT; ++r) {
            float pt[4] = {0.f, 0.f, 0.f, 0.f}, pn[4] = {0.f, 0.f, 0.f, 0.f};
#pragma unroll
            for (int c = 0; c < 4; ++c)
#pragma unroll
                for (int reg = 0; reg < 4; ++reg) {
                    pt[reg] += acc[r][c][reg] * at[c];
                    pn[reg] += acc[r][c][reg] * an[c];
                }
#pragma unroll
            for (int reg = 0; reg < 4; ++reg)
#pragma unroll
                for (int m = 1; m < 16; m <<= 1) {
                    pt[reg] += __shfl_xor(pt[reg], m);
                    pn[reg] += __shfl_xor(pn[reg], m);
                }
            if (l16 == 0) {
#pragma unroll
                for (int reg = 0; reg < 4; ++reg) {
                    int row = row0 + r * 16 + quad * 4 + reg;
                    if (row < M) {
                        s_t[wave * M + row] = pt[reg];
                        s_n[wave * M + row] = pn[reg];
                    }
                }
            }
        }
    }
}

// ---------------- launch 2: GEMM1 (fp32 A) + fused scores ---------------------------
__global__ __launch_bounds__(256) void gemm1_kernel(
    const float* __restrict__ x, const float* __restrict__ a0,
    const ushort* __restrict__ Bh, const ushort* __restrict__ Bl,
    float* __restrict__ h0, float* __restrict__ s_t, float* __restrict__ s_n)
{
    __shared__ ushort sah[32 * LDP];
    __shared__ ushort sal[32 * LDP];
    gemm_tile<2, 0, 1, 1>(blockIdx.x * 32, N2C, x, Bh, Bl, nullptr, a0,
                          h0, s_t, s_n, sah, sal);
}

// ---------------- launches 3/4: fused attention -> GEMM -----------------------------
// Block = 16 targets. Wave w does target r*4+w per round r: wave-parallel softmax
// (lane=edge, dedupe via shfl scan) then gather (lane=channel-quad, 33 batched
// float4 loads), result written as bf16 hi/lo straight into the GEMM's LDS A-tile.
// No grid sync needed: x1/x2 rows live only in LDS. Launch boundary provides the
// h/s dependency sync (no 70us device-scope barriers — R7/R8 lesson).
template<int EPI, int SC>
__global__ __launch_bounds__(256) void ag_kernel(
    const float* __restrict__ hprev, const int* __restrict__ nbr_arr,
    const float* __restrict__ s_tin, const float* __restrict__ s_nin,
    const ushort* __restrict__ Bh, const ushort* __restrict__ Bl,
    const float* __restrict__ bias, const float* __restrict__ avec,
    float* __restrict__ out, float* __restrict__ s_tout, float* __restrict__ s_nout,
    int T, int Nsrc)
{
    __shared__ ushort sah[16 * LDP];
    __shared__ ushort sal[16 * LDP];
    __shared__ float wts[4][NHEAD][DEG + 2];

    const int wave = threadIdx.x >> 6;
    const int lane = threadIdx.x & 63;
    const int row0 = blockIdx.x * 16;
    const float4* hp4 = (const float4*)hprev;

#pragma unroll
    for (int r = 0; r < 4; ++r) {
        const int tg = r * 4 + wave;
        const int tgt = row0 + tg;
        if (tgt < T) {                       // wave-uniform condition
            int me = 0;
            if (lane < DEG) me = nbr_arr[tgt * DEG + lane];
            else if (lane == DEG) me = nbr_arr[T * DEG + tgt];   // self-loop edge
            int k = (lane <= DEG) ? 1 : 0;
#pragma unroll
            for (int j = 0; j < DEG; ++j) {  // keep-first dedupe scan
                int v = __shfl(me, j);
                if (j < lane && v == me) k = 0;
            }
#pragma unroll
            for (int hd = 0; hd < NHEAD; ++hd) {
                float e = s_tin[hd * Nsrc + tgt] + s_nin[hd * Nsrc + me];
                e = (e >= 0.f) ? e : ALPHA * e;          // LeakyReLU(0.2)
                float em = k ? e : -1e30f;
                float m = em;
#pragma unroll
                for (int off = 1; off < 64; off <<= 1) m = fmaxf(m, __shfl_xor(m, off));
                float w = k ? __expf(e - m) : 0.f;
                float Z = w;
#pragma unroll
                for (int off = 1; off < 64; off <<= 1) Z += __shfl_xor(Z, off);
                if (lane <= DEG) wts[wave][hd][lane] = w / Z;
            }
            // gather: lane = channel-quad; 33 unconditional batched float4 loads
            const int hd = lane >> 4;
            float4 acc = make_float4(0.f, 0.f, 0.f, 0.f);
#pragma unroll
            for (int e = 0; e <= DEG; ++e) {
                int row = __shfl(me, e);                 // wave-uniform
                float wt = wts[wave][hd][e];             // dups: wt==0
                float4 v = hp4[(size_t)row * 64 + lane];
                acc.x += wt * v.x; acc.y += wt * v.y;
                acc.z += wt * v.z; acc.w += wt * v.w;
            }
            acc.x = (acc.x > 0.f) ? acc.x : expm1f(acc.x);   // ELU
            acc.y = (acc.y > 0.f) ? acc.y : expm1f(acc.y);
            acc.z = (acc.z > 0.f) ? acc.z : expm1f(acc.z);
            acc.w = (acc.w > 0.f) ? acc.w : expm1f(acc.w);
            ushort4 h, l;
            h.x = f2bf(acc.x); l.x = f2bf(acc.x - bf2f(h.x));
            h.y = f2bf(acc.y); l.y = f2bf(acc.y - bf2f(h.y));
            h.z = f2bf(acc.z); l.z = f2bf(acc.z - bf2f(h.z));
            h.w = f2bf(acc.w); l.w = f2bf(acc.w - bf2f(h.w));
            *(ushort4*)(&sah[tg * LDP + lane * 4]) = h;
            *(ushort4*)(&sal[tg * LDP + lane * 4]) = l;
        } else {
            ushort4 z = make_ushort4(0, 0, 0, 0);
            *(ushort4*)(&sah[tg * LDP + lane * 4]) = z;
            *(ushort4*)(&sal[tg * LDP + lane * 4]) = z;
        }
    }
    __syncthreads();
    gemm_tile<1, EPI, 2, SC>(row0, T, nullptr, Bh, Bl, bias, avec,
                             out, s_tout, s_nout, sah, sal);
}

extern "C" void kernel_launch(void* const* d_in, const int* in_sizes, int n_in,
                              void* d_out, int out_size, void* d_ws, size_t ws_size,
                              hipStream_t stream)
{
    const float* x    = (const float*)d_in[0];
    const float* W0   = (const float*)d_in[1];
    const float* a0   = (const float*)d_in[2];
    const float* W1   = (const float*)d_in[3];
    const float* a1   = (const float*)d_in[4];
    const float* linW = (const float*)d_in[5];
    const float* linb = (const float*)d_in[6];
    const int* adj1_nbr = (const int*)d_in[8];
    const int* adj0_nbr = (const int*)d_in[10];
    char* ws = (char*)d_ws;

    // workspace layout (bytes); h1 and layer-2 scores get OWN buffers: producer and
    // consumer now share a launch, so no aliasing with h0 / layer-1 scores.
    ushort* Wth = (ushort*)ws;                      // 0        (393216 B)
    ushort* Wtl = (ushort*)(ws + 393216);           // 393216   (393216 B)
    float*  st0 = (float*)(ws + 786432);            // 4*16000 f32
    float*  sn0 = (float*)(ws + 1048576);
    float*  st1 = (float*)(ws + 1310720);           // 4*4000 f32
    float*  sn1 = (float*)(ws + 1376256);
    float*  h0  = (float*)(ws + 1441792);           // 16000*256 f32
    float*  h1  = (float*)(ws + 17825792);          // 4000*256 f32

    repack_kernel<<<768, 256, 0, stream>>>(W0, W1, linW, Wth, Wtl);

    gemm1_kernel<<<N2C / 32, 256, 0, stream>>>(x, a0, Wth, Wtl, h0, st0, sn0);

    ag_kernel<0, 1><<<N1C / 16, 256, 0, stream>>>(
        h0, adj1_nbr, st0, sn0, Wth + 65536, Wtl + 65536, nullptr, a1,
        h1, st1, sn1, N1C, N2C);

    ag_kernel<1, 0><<<(N0C + 15) / 16, 256, 0, stream>>>(
        h1, adj0_nbr, st1, sn1, Wth + 131072, Wtl + 131072, linb, nullptr,
        (float*)d_out, nullptr, nullptr, N0C, N1C);
}